// Round 12
// baseline (25011.737 us; speedup 1.0000x reference)
//
#include <hip/hip_runtime.h>
#include <hip/hip_bf16.h>

// ---------------- types ----------------
typedef _Float16 half2_t __attribute__((ext_vector_type(2)));
typedef _Float16 half8_t __attribute__((ext_vector_type(8)));
typedef float float4_t __attribute__((ext_vector_type(4)));

#define SEQ   8192
#define ISZ   512
#define HID   2048
#define G4H   8192   // 4*HID
#define NB    128    // persistent blocks (R12: halved participants)
#define NT    512    // threads per block (8 waves)

#if __has_builtin(__builtin_amdgcn_fdot2)
#define DOT2(a, b, c) __builtin_amdgcn_fdot2((a), (b), (c), false)
#else
static __device__ __forceinline__ float DOT2(half2_t a, half2_t b, float c) {
    return c + (float)a.x * (float)b.x + (float)a.y * (float)b.y;
}
#endif

#if __has_builtin(__builtin_amdgcn_rcpf)
#define RCP(x) __builtin_amdgcn_rcpf(x)
#else
#define RCP(x) (1.0f / (x))
#endif

// relaxed agent-scope (sc1, device-coherent) accesses — no fences, no RMW
static __device__ __forceinline__ unsigned long long ld_u64(const void* p) {
    return __hip_atomic_load((const unsigned long long*)p, __ATOMIC_RELAXED,
                             __HIP_MEMORY_SCOPE_AGENT);
}
static __device__ __forceinline__ void st_u64(void* p, unsigned long long v) {
    __hip_atomic_store((unsigned long long*)p, v, __ATOMIC_RELAXED,
                       __HIP_MEMORY_SCOPE_AGENT);
}

// DPP butterfly add: x + perm(x).
template <int CTRL>
static __device__ __forceinline__ float dpp_add(float x) {
    int v = __builtin_amdgcn_update_dpp(0, __builtin_bit_cast(int, x), CTRL, 0xF,
                                        0xF, true);
    return x + __builtin_bit_cast(float, v);
}
#define DPP_XOR1  0xB1   // quad_perm [1,0,3,2]
#define DPP_XOR2  0x4E   // quad_perm [2,3,0,1]
#define DPP_XOR4  0x141  // row_half_mirror
#define DPP_XOR8  0x128  // row_ror:8 (exact lane s <-> s+8 within row16)

#define TAGOK(v, t) ((unsigned)((v) >> 32) >= (t))

// ---------------- f32 -> f16 convert ----------------
__global__ __launch_bounds__(256) void cvt_f32_f16(const float* __restrict__ in,
                                                   _Float16* __restrict__ out, int n) {
    int i = (blockIdx.x * 256 + threadIdx.x) * 4;
    if (i < n) {
        float4 v = *(const float4*)(in + i);
        out[i + 0] = (_Float16)v.x;
        out[i + 1] = (_Float16)v.y;
        out[i + 2] = (_Float16)v.z;
        out[i + 3] = (_Float16)v.w;
    }
}

// ---------------- init words (zero => {h=0, tag=0} == "h_0 valid") ----------------
// words[2][128][8] u64: block b's record = one 64-B line of 8 fused words.
__global__ __launch_bounds__(256) void init_state(unsigned long long* __restrict__ words) {
    int i = blockIdx.x * 256 + threadIdx.x;
    if (i < 2048) words[i] = 0ull;
}

// ---------------- x_proj GEMM: C = A @ B^T, epilogue scattered into xp2 ----------
// xp2 layout: xp2[t][blk*64 + w*8 + r], r = gate*2 + (e&1), w = (e>>1)&7,
// blk = e>>4 (e = col & 2047, gate = col >> 11). Two 64-B lines per block-step.
__global__ __launch_bounds__(256) void gemm_xproj(const _Float16* __restrict__ A,  // [SEQ][ISZ]
                                                  const _Float16* __restrict__ B,  // [G4H][ISZ]
                                                  _Float16* __restrict__ C) {      // [SEQ][G4H] permuted
    __shared__ _Float16 As[128 * 40];
    __shared__ _Float16 Bs[128 * 40];
    const int tid = threadIdx.x;
    const int bm = blockIdx.y, bn = blockIdx.x;
    const int wave = tid >> 6, lane = tid & 63;
    const int wr = wave >> 1, wc = wave & 1;
    const int l15 = lane & 15, lq = lane >> 4;

    float4_t acc[4][4];
#pragma unroll
    for (int im = 0; im < 4; im++)
#pragma unroll
        for (int in = 0; in < 4; in++)
#pragma unroll
            for (int r = 0; r < 4; r++) acc[im][in][r] = 0.f;

    for (int kt = 0; kt < ISZ; kt += 32) {
        __syncthreads();
#pragma unroll
        for (int ld = 0; ld < 2; ld++) {
            int c = tid + ld * 256;
            int r = c >> 2, ko = (c & 3) * 8;
            uint4 av = *(const uint4*)(A + (size_t)(bm * 128 + r) * ISZ + kt + ko);
            *(uint4*)(As + r * 40 + ko) = av;
            uint4 bv = *(const uint4*)(B + (size_t)(bn * 128 + r) * ISZ + kt + ko);
            *(uint4*)(Bs + r * 40 + ko) = bv;
        }
        __syncthreads();
        half8_t af[4], bf[4];
#pragma unroll
        for (int im = 0; im < 4; im++)
            af[im] = *(half8_t*)(As + (wr * 64 + im * 16 + l15) * 40 + lq * 8);
#pragma unroll
        for (int in = 0; in < 4; in++)
            bf[in] = *(half8_t*)(Bs + (wc * 64 + in * 16 + l15) * 40 + lq * 8);
#pragma unroll
        for (int im = 0; im < 4; im++)
#pragma unroll
            for (int in = 0; in < 4; in++)
                acc[im][in] = __builtin_amdgcn_mfma_f32_16x16x32_f16(af[im], bf[in], acc[im][in], 0, 0, 0);
    }
#pragma unroll
    for (int im = 0; im < 4; im++) {
        int mg = bm * 128 + wr * 64 + im * 16 + lq * 4;
#pragma unroll
        for (int in = 0; in < 4; in++) {
            int ng = bn * 128 + wc * 64 + in * 16 + l15;
            int gate = ng >> 11;
            int e = ng & 2047;
            int col2 = (e >> 4) * 64 + ((e >> 1) & 7) * 8 + gate * 2 + (e & 1);
#pragma unroll
            for (int r = 0; r < 4; r++)
                C[(size_t)(mg + r) * G4H + col2] = (_Float16)acc[im][in][r];
        }
    }
}

// ---------------- persistent LSTM recurrence ----------------
// R12: 128 blocks x 512 threads. Block b owns h[16b..16b+16); wave w (0..7)
// owns all 4 gates of elements {16b+2w, 16b+2w+1} — inner structure identical
// to R7 (8 rows x 32 cols/lane). Exchange: 1024 fused words {tag|h_e1|h_e0},
// word id = sb*8+w covers elements [2*wid, 2*wid+2); block's 8 words = ONE
// 64-B line (128 lines total, halved vs R7; skew = max-of-128).
// Thread tid polls 2 words of source block sb = ((tid>>2)+b)&127, pair k=tid&3.
__global__ __launch_bounds__(512, 1) void lstm_persist(
    const float* __restrict__ Whh,   // [G4H][HID] f32
    const float* __restrict__ b_ih, const float* __restrict__ b_hh,
    const _Float16* __restrict__ xp, // [SEQ][G4H] f16, permuted layout
    const float* __restrict__ fcw, const float* __restrict__ fcb,
    unsigned long long* __restrict__ words,  // [2][128][8]
    float* __restrict__ out) {
    const int b = blockIdx.x, tid = threadIdx.x;
    const int g = tid >> 6, lane = tid & 63;
    const int sb = ((tid >> 2) + b) & 127;  // source block this thread polls
    const int k = tid & 3;                  // word pair within sb

    __shared__ unsigned h_lds32[2][1280];  // parity x (64 units x 20 dwords)

    // --- prologue: weight slice into registers (f32 -> f16) ---
    half2_t w[8][16];
#pragma unroll
    for (int r = 0; r < 8; r++) {
        const float* wp =
            Whh + (size_t)((r >> 1) * HID + b * 16 + 2 * g + (r & 1)) * HID + lane * 32;
#pragma unroll
        for (int i = 0; i < 16; i++) {
            float2 f = *(const float2*)(wp + i * 2);
            half2_t h2;
            h2.x = (_Float16)f.x;
            h2.y = (_Float16)f.y;
            w[r][i] = h2;
        }
    }
    float bias_r = 0.f;
    if (lane < 8) {
        int row = ((lane >> 1) & 3) * HID + b * 16 + 2 * g + (lane & 1);
        bias_r = b_ih[row] + b_hh[row];
    }
    float c_reg = 0.f;  // cell state of elem 2g+(lane&1)

    const int s_dw = (sb >> 1) * 20 + 8 * (sb & 1) + 2 * k;  // LDS stage dst
    const int xpbase = b * 64 + g * 8;                       // + lane (lanes 0..7)
    const int pwid = sb * 8 + 2 * k;                         // first polled word id

    // xp prefetch pipeline: xpv_cur holds xp[t] by loop entry
    float xpv_cur = 0.f;
    if (lane < 8) xpv_cur = (float)xp[xpbase + lane];

    for (int t = 0; t < SEQ; ++t) {
        const unsigned ut = (unsigned)t;
        const int par = t & 1;

        // prefetch xp[t+1]; independent of everything -> overlaps whole step
        float xpv_next = 0.f;
        if (lane < 8 && t + 1 < SEQ)
            xpv_next = (float)xp[(size_t)(t + 1) * G4H + xpbase + lane];
        const float xpv = xpv_cur;

        // poll this thread's 2 self-validating words
        const unsigned long long* wp = words + (size_t)par * 1024 + pwid;
        unsigned long long v0, v1;
        for (;;) {
            v0 = ld_u64(wp + 0);
            v1 = ld_u64(wp + 1);
            if (__all(TAGOK(v0, ut) && TAGOK(v1, ut))) break;
            __builtin_amdgcn_s_sleep(1);
        }

        // stage 4 halves into parity LDS buffer (one 8-B write)
        *(uint2*)&h_lds32[par][s_dw] = make_uint2((unsigned)v0, (unsigned)v1);
        __syncthreads();  // the ONLY barrier: h_t fully staged

        // read slice [lane*32, lane*32+32) as 4 x b128 (80-B units)
        union {
            uint4 q[4];
            half2_t h2[16];
        } hu;
        const uint4* hp4 = (const uint4*)((const char*)&h_lds32[par][0] + 80 * lane);
#pragma unroll
        for (int i = 0; i < 4; i++) hu.q[i] = hp4[i];

        // matvec: 8 rows x 32 cols per lane
        float acc[8];
#pragma unroll
        for (int r = 0; r < 8; r++) {
            float a = 0.f;
#pragma unroll
            for (int i = 0; i < 16; i++) a = DOT2(w[r][i], hu.h2[i], a);
            acc[r] = a;
        }
        // reduce: DPP xor1/2/4, select, DPP xor8, shfl 16/32
#pragma unroll
        for (int r = 0; r < 8; r++) {
            acc[r] = dpp_add<DPP_XOR1>(acc[r]);
            acc[r] = dpp_add<DPP_XOR2>(acc[r]);
            acc[r] = dpp_add<DPP_XOR4>(acc[r]);
        }
        float u;
        {
            int s = lane & 7;
            float u01 = (s & 1) ? acc[1] : acc[0];
            float u23 = (s & 1) ? acc[3] : acc[2];
            float u45 = (s & 1) ? acc[5] : acc[4];
            float u67 = (s & 1) ? acc[7] : acc[6];
            float ua = (s & 2) ? u23 : u01;
            float ub = (s & 2) ? u67 : u45;
            u = (s & 4) ? ub : ua;
        }
        u = dpp_add<DPP_XOR8>(u);
        u += __shfl_xor(u, 16, 64);
        u += __shfl_xor(u, 32, 64);
        u += bias_r + xpv;  // valid in lanes 0..7 (sources of the gate shfls)

        // gates: rows [i_e0,i_e1,f_e0,f_e1,g_e0,g_e1,o_e0,o_e1] in lanes 0..7
        {
            int base = lane & 1;
            float gi = __shfl(u, base + 0, 64);
            float gf = __shfl(u, base + 2, 64);
            float gg = __shfl(u, base + 4, 64);
            float go = __shfl(u, base + 6, 64);
            float si = RCP(1.f + __expf(-gi));
            float sf = RCP(1.f + __expf(-gf));
            float so = RCP(1.f + __expf(-go));
            float tg = 1.f - 2.f * RCP(1.f + __expf(2.f * gg));
            c_reg = sf * c_reg + si * tg;
            float tc = 1.f - 2.f * RCP(1.f + __expf(2.f * c_reg));
            float h = so * tc;
            _Float16 hf = (_Float16)h;
            unsigned pk = *(unsigned short*)&hf;
            unsigned pk1 = __shfl(pk, 1, 64);
            if (lane == 0) {
                unsigned lo = pk | (pk1 << 16);
                unsigned long long wword =
                    (unsigned long long)lo | ((unsigned long long)(ut + 1) << 32);
                st_u64(words + (size_t)((t + 1) & 1) * 1024 + b * 8 + g, wword);
            }
        }
        xpv_cur = xpv_next;
        // parity-double-buffered LDS + B1 ordering make cross-step reuse race-free
    }

    // --- final fc on h_SEQ (parity 0) by block 0 ---
    if (b == 0) {
        const int par = SEQ & 1;
        const unsigned long long* wp = words + (size_t)par * 1024 + pwid;
        unsigned long long v0, v1;
        for (;;) {
            v0 = ld_u64(wp + 0);
            v1 = ld_u64(wp + 1);
            if (__all(TAGOK(v0, (unsigned)SEQ) && TAGOK(v1, (unsigned)SEQ))) break;
            __builtin_amdgcn_s_sleep(1);
        }
        *(uint2*)&h_lds32[par][s_dw] = make_uint2((unsigned)v0, (unsigned)v1);
        __syncthreads();
        if (g == 0) {
            union {
                uint4 q[4];
                half2_t h2[16];
            } hu;
            const uint4* hp4 = (const uint4*)((const char*)&h_lds32[par][0] + 80 * lane);
#pragma unroll
            for (int i = 0; i < 4; i++) hu.q[i] = hp4[i];
            float s = 0.f;
            const float* fw = fcw + lane * 32;
#pragma unroll
            for (int i = 0; i < 16; i++)
                s += (float)hu.h2[i].x * fw[2 * i] + (float)hu.h2[i].y * fw[2 * i + 1];
#pragma unroll
            for (int off = 1; off < 64; off <<= 1) s += __shfl_xor(s, off, 64);
            if (lane == 0) out[0] = s + fcb[0];
        }
    }
}

// ---------------- launch ----------------
extern "C" void kernel_launch(void* const* d_in, const int* in_sizes, int n_in,
                              void* d_out, int out_size, void* d_ws, size_t ws_size,
                              hipStream_t stream) {
    const float* input = (const float*)d_in[0];  // [SEQ][ISZ]
    const float* W_ih = (const float*)d_in[1];   // [G4H][ISZ]
    const float* W_hh = (const float*)d_in[2];   // [G4H][HID]
    const float* b_ih = (const float*)d_in[3];
    const float* b_hh = (const float*)d_in[4];
    const float* fc_w = (const float*)d_in[5];
    const float* fc_b = (const float*)d_in[6];
    float* out = (float*)d_out;

    char* ws = (char*)d_ws;
    _Float16* xp16 = (_Float16*)ws;               // 134,217,728 B
    _Float16* A16 = (_Float16*)(ws + 134217728);  // 8 MB (dead after gemm)
    _Float16* B16 = (_Float16*)(ws + 142606336);  // 8 MB (dead after gemm)
    // words overlay the dead A16 region (init_state runs AFTER gemm): 16 KB
    unsigned long long* words = (unsigned long long*)(ws + 134217728);

    cvt_f32_f16<<<(SEQ * ISZ) / 1024, 256, 0, stream>>>(input, A16, SEQ * ISZ);
    cvt_f32_f16<<<(G4H * ISZ) / 1024, 256, 0, stream>>>(W_ih, B16, G4H * ISZ);

    dim3 gg(G4H / 128, SEQ / 128);
    gemm_xproj<<<gg, 256, 0, stream>>>(A16, B16, xp16);

    init_state<<<8, 256, 0, stream>>>(words);  // after gemm: A16 region is dead

    lstm_persist<<<NB, NT, 0, stream>>>(W_hh, b_ih, b_hh, xp16, fc_w, fc_b,
                                        words, out);
}